// Round 3
// baseline (95.325 us; speedup 1.0000x reference)
//
#include <hip/hip_runtime.h>
#include <math.h>

#define ALPHA 0.2f
#define LOG2E 1.4426950408889634f

constexpr int B = 32, N = 1024;
constexpr int TI = 64;          // i-rows per attn block (4 MFMA i-groups)

typedef __attribute__((ext_vector_type(8))) short short8;
typedef __attribute__((ext_vector_type(4))) float floatx4;

static __device__ __forceinline__ unsigned f32bf(float f) {
    unsigned u = __float_as_uint(f);
    return (u + 0x7FFFu + ((u >> 16) & 1u)) >> 16;   // RNE, no NaN inputs here
}

// ---------------- Kernel P (fused): hs-role blocks [0,512) + mask-role -----
// hs-role: h(bf16) in MFMA-B-fragment layout hT2[b][jt][t][cg][fq][il][e];
//          also writes es=e^s, es2=e^{0.2s}, ed=e^d, ed2=e^{0.2d} per node
//          (exp(lrelu(s+d)) = max(es*ed, es2*ed2) since exp2 is monotone).
// mask-role blocks [512,4608): adj -> bitmask ballot.
__global__ __launch_bounds__(256) void gat_pre(const float* __restrict__ input,
                                               const float* __restrict__ adj,
                                               const float* __restrict__ Wm,
                                               const float* __restrict__ a,
                                               unsigned short* __restrict__ hT2,
                                               unsigned long long* __restrict__ mask64,
                                               float* __restrict__ es,
                                               float* __restrict__ es2,
                                               float* __restrict__ ed,
                                               float* __restrict__ ed2)
{
    const int tid  = threadIdx.x;
    const int lane = tid & 63;
    const int wave = tid >> 6;

    if (blockIdx.x >= 512) {                     // ---- mask role ----
        const int id = (blockIdx.x - 512) * 4 + wave;   // 0..16383
        const int i  = id >> 4;
        const int jc = id & 15;
        const float av = adj[(size_t)i * N + jc * 64 + lane];
        const unsigned long long bal = __ballot(av > 0.5f);
        if (lane == 0) mask64[i * 16 + jc] = bal;
        return;
    }

    // ---- hs role ----
    __shared__ __align__(16) float ins[64 * 68];          // padded rows
    __shared__ __align__(16) unsigned short hsT[64 * 72]; // [c][row] padded
    __shared__ float red_s[256], red_d[256];
    __shared__ float wa_l[128];

    const int row0 = blockIdx.x * 64;
    const int b    = row0 >> 10;
    const int jb   = row0 & 1023;

    float wreg[64];
#pragma unroll
    for (int k = 0; k < 64; ++k) wreg[k] = Wm[k * 64 + lane];   // W[:,lane]

    const float4* gin = (const float4*)(input + (size_t)row0 * 64);
#pragma unroll
    for (int s = 0; s < 4; ++s) {
        const int id = tid + 256 * s;
        *(float4*)&ins[(id >> 4) * 68 + (id & 15) * 4] = gin[id];
    }
    if (wave == 0) {                             // wa[k] = sum_c W[k][c]*a[c]
        float accs = 0.f, accd = 0.f;
#pragma unroll
        for (int c4 = 0; c4 < 16; ++c4) {
            const float4 wv = *(const float4*)&Wm[lane * 64 + c4 * 4];
            const float4 as = *(const float4*)&a[c4 * 4];
            const float4 ad = *(const float4*)&a[64 + c4 * 4];
            accs = fmaf(wv.x, as.x, fmaf(wv.y, as.y, fmaf(wv.z, as.z, fmaf(wv.w, as.w, accs))));
            accd = fmaf(wv.x, ad.x, fmaf(wv.y, ad.y, fmaf(wv.z, ad.z, fmaf(wv.w, ad.w, accd))));
        }
        wa_l[lane] = accs;
        wa_l[64 + lane] = accd;
    }
    __syncthreads();

    // h rows: wave handles rows [wave*16, wave*16+16)
    for (int r = 0; r < 16; ++r) {
        const int row = wave * 16 + r;
        float acc = 0.f;
#pragma unroll
        for (int k4 = 0; k4 < 16; ++k4) {
            const float4 iv = *(const float4*)&ins[row * 68 + k4 * 4];   // uniform
            acc = fmaf(iv.x, wreg[k4 * 4 + 0], acc);
            acc = fmaf(iv.y, wreg[k4 * 4 + 1], acc);
            acc = fmaf(iv.z, wreg[k4 * 4 + 2], acc);
            acc = fmaf(iv.w, wreg[k4 * 4 + 3], acc);
        }
        hsT[lane * 72 + row] = (unsigned short)f32bf(acc);   // transpose in LDS
    }

    // s_src/s_dst = ins @ wa (exact fp32, independent of bf16 h)
    {
        const int r = tid & 63, kq = tid >> 6;
        float as = 0.f, ad = 0.f;
#pragma unroll
        for (int t = 0; t < 4; ++t) {
            const float4 iv = *(const float4*)&ins[r * 68 + kq * 16 + t * 4];
            const float4 ws = *(const float4*)&wa_l[kq * 16 + t * 4];
            const float4 wd = *(const float4*)&wa_l[64 + kq * 16 + t * 4];
            as = fmaf(iv.x, ws.x, fmaf(iv.y, ws.y, fmaf(iv.z, ws.z, fmaf(iv.w, ws.w, as))));
            ad = fmaf(iv.x, wd.x, fmaf(iv.y, wd.y, fmaf(iv.z, wd.z, fmaf(iv.w, wd.w, ad))));
        }
        red_s[tid] = as;
        red_d[tid] = ad;
    }
    __syncthreads();

    if (tid < 64) {
        const float ss = (red_s[tid] + red_s[tid + 64] + red_s[tid + 128] + red_s[tid + 192]) * LOG2E;
        const float dd = (red_d[tid] + red_d[tid + 64] + red_d[tid + 128] + red_d[tid + 192]) * LOG2E;
        es [row0 + tid] = __builtin_amdgcn_exp2f(ss);
        es2[row0 + tid] = __builtin_amdgcn_exp2f(0.2f * ss);
        ed [row0 + tid] = __builtin_amdgcn_exp2f(dd);
        ed2[row0 + tid] = __builtin_amdgcn_exp2f(0.2f * dd);
    }

    // hT2 store: thread tid writes chunks q=2*tid, 2*tid+1 (32 B contiguous)
    {
        const int il2 = (tid & 7) * 2;
        const int fq  = (tid >> 3) & 3;
        const int cg  = (tid >> 5) & 3;
        const int t   = tid >> 7;
        const int c   = cg * 16 + il2;
        const int off = t * 32 + fq * 8;
        const short8 v0 = *(const short8*)&hsT[c * 72 + off];
        const short8 v1 = *(const short8*)&hsT[(c + 1) * 72 + off];
        unsigned short* g = hT2 + (((size_t)b * 16 + (jb >> 6)) << 12) + tid * 16;
        *(short8*)&g[0] = v0;
        *(short8*)&g[8] = v1;
    }
}

// ---------------- Kernel B: barrier-free, trans-free softmax + MFMA + ELU --
// TI=64 rows per block; wave w owns j-quarter {it*4+w}. Inner element:
// p = mask ? max(E*D, E2*D2) : 0  (2 mul + max + cndmask, no exp).
// Zero LDS / zero barriers in the main loop; one epilogue barrier.
__global__ __launch_bounds__(256) void gat_attn(const unsigned short* __restrict__ hT2,
                                                const float* __restrict__ es,
                                                const float* __restrict__ es2,
                                                const float* __restrict__ ed,
                                                const float* __restrict__ ed2,
                                                const unsigned* __restrict__ mask32,
                                                float* __restrict__ out)
{
    __shared__ __align__(16) float red[4][64][68];   // 69.6 KB
    __shared__ float pps[4][4][16];

    const int tid  = threadIdx.x;
    const int lane = tid & 63;
    const int w    = tid >> 6;
    // chunked XCD swizzle: 512 blocks, 64 consecutive per XCD -> 4 batches/XCD-L2
    const int bid  = (blockIdx.x & 7) * 64 + (blockIdx.x >> 3);
    const int b    = bid >> 4;
    const int i0   = (bid & 15) * TI;

    const int il  = lane & 15;
    const int fq  = lane >> 4;
    const int fsh = fq * 8;

    float E[4], E2[4];
#pragma unroll
    for (int ig = 0; ig < 4; ++ig) {
        E[ig]  = es [b * N + i0 + ig * 16 + il];
        E2[ig] = es2[b * N + i0 + ig * 16 + il];
    }
    const float* edb  = ed  + b * N;
    const float* ed2b = ed2 + b * N;

    floatx4 acc[4][4];
#pragma unroll
    for (int ig = 0; ig < 4; ++ig)
#pragma unroll
        for (int cg = 0; cg < 4; ++cg) acc[ig][cg] = (floatx4){0.f, 0.f, 0.f, 0.f};
    float ps[4] = {0.f, 0.f, 0.f, 0.f};

    union Af { short8 v; unsigned u[4]; };

    for (int it = 0; it < 4; ++it) {
        const int jt = it * 4 + w;                    // this wave's j-tile
        const unsigned short* hp = hT2 + (((size_t)b * 16 + jt) << 12) + lane * 8;
        uint2 m[4];
#pragma unroll
        for (int ig = 0; ig < 4; ++ig)
            m[ig] = *(const uint2*)&mask32[(size_t)(i0 + ig * 16 + il) * 32 + jt * 2];

#pragma unroll
        for (int t = 0; t < 2; ++t) {
            const int j0 = jt * 64 + t * 32 + fsh;
            const float4 d0 = *(const float4*)&edb[j0];
            const float4 d1 = *(const float4*)&edb[j0 + 4];
            const float4 g0 = *(const float4*)&ed2b[j0];
            const float4 g1 = *(const float4*)&ed2b[j0 + 4];
            short8 bf[4];
#pragma unroll
            for (int cg = 0; cg < 4; ++cg)
                bf[cg] = *(const short8*)(hp + (t * 4 + cg) * 512);

            float dv[8], gv[8];
            *(float4*)&dv[0] = d0; *(float4*)&dv[4] = d1;
            *(float4*)&gv[0] = g0; *(float4*)&gv[4] = g1;

            Af af[4];
#pragma unroll
            for (int ig = 0; ig < 4; ++ig) {
                const unsigned mbits = (t ? m[ig].y : m[ig].x) >> fsh;
                float p[8];
#pragma unroll
                for (int e = 0; e < 8; ++e) {
                    const float x = fmaxf(E[ig] * dv[e], E2[ig] * gv[e]);  // exp(lrelu)
                    p[e] = ((mbits >> e) & 1u) ? x : 0.f;
                }
                ps[ig] += ((p[0] + p[1]) + (p[2] + p[3])) + ((p[4] + p[5]) + (p[6] + p[7]));
#pragma unroll
                for (int q = 0; q < 4; ++q) {
                    unsigned r;
                    asm("v_cvt_pk_bf16_f32 %0, %1, %2" : "=v"(r) : "v"(p[q * 2]), "v"(p[q * 2 + 1]));
                    af[ig].u[q] = r;
                }
            }
#pragma unroll
            for (int ig = 0; ig < 4; ++ig)
#pragma unroll
                for (int cg = 0; cg < 4; ++cg)
                    acc[ig][cg] = __builtin_amdgcn_mfma_f32_16x16x32_bf16(af[ig].v, bf[cg], acc[ig][cg], 0, 0, 0);
        }
    }

    // row-sums: lanes {il, il+16, il+32, il+48} hold disjoint fq-slices
#pragma unroll
    for (int ig = 0; ig < 4; ++ig) {
        ps[ig] += __shfl_xor(ps[ig], 16);
        ps[ig] += __shfl_xor(ps[ig], 32);
    }
    if (lane < 16)
#pragma unroll
        for (int ig = 0; ig < 4; ++ig) pps[w][ig][lane] = ps[ig];

    // C/D layout: col = cg*16 + il, row = ig*16 + fq*4 + r
#pragma unroll
    for (int ig = 0; ig < 4; ++ig)
#pragma unroll
        for (int cg = 0; cg < 4; ++cg)
#pragma unroll
            for (int r = 0; r < 4; ++r)
                red[w][ig * 16 + fq * 4 + r][cg * 16 + il] = acc[ig][cg][r];
    __syncthreads();

    // cross-wave reduce + softmax divide + ELU + store (thread: 1 row x 16 cols)
    const int row = tid >> 2;
    const int c0  = (tid & 3) * 16;
    const int ig  = row >> 4, rl = row & 15;
    const float inv = 1.f / (pps[0][ig][rl] + pps[1][ig][rl] + pps[2][ig][rl] + pps[3][ig][rl]);
    float* op = out + ((size_t)(b * N + i0 + row)) * 64 + c0;
#pragma unroll
    for (int q = 0; q < 4; ++q) {
        const float4 v0 = *(const float4*)&red[0][row][c0 + q * 4];
        const float4 v1 = *(const float4*)&red[1][row][c0 + q * 4];
        const float4 v2 = *(const float4*)&red[2][row][c0 + q * 4];
        const float4 v3 = *(const float4*)&red[3][row][c0 + q * 4];
        float o[4];
        o[0] = ((v0.x + v1.x) + (v2.x + v3.x)) * inv;
        o[1] = ((v0.y + v1.y) + (v2.y + v3.y)) * inv;
        o[2] = ((v0.z + v1.z) + (v2.z + v3.z)) * inv;
        o[3] = ((v0.w + v1.w) + (v2.w + v3.w)) * inv;
#pragma unroll
        for (int e = 0; e < 4; ++e)
            o[e] = o[e] > 0.f ? o[e] : __expf(o[e]) - 1.f;      // ELU
        *(float4*)&op[q * 4] = *(const float4*)&o[0];
    }
}

extern "C" void kernel_launch(void* const* d_in, const int* in_sizes, int n_in,
                              void* d_out, int out_size, void* d_ws, size_t ws_size,
                              hipStream_t stream) {
    const float* input = (const float*)d_in[0];
    const float* adj   = (const float*)d_in[1];
    const float* Wm    = (const float*)d_in[2];
    const float* a     = (const float*)d_in[3];
    float* out = (float*)d_out;

    char* ws = (char*)d_ws;
    unsigned short* hT2 = (unsigned short*)ws;                     // 4 MB
    float* es  = (float*)(ws + 4194304);                           // 128 KB
    float* es2 = (float*)(ws + 4194304 + 131072);                  // 128 KB
    float* ed  = (float*)(ws + 4194304 + 2 * 131072);              // 128 KB
    float* ed2 = (float*)(ws + 4194304 + 3 * 131072);              // 128 KB
    unsigned long long* mask64 = (unsigned long long*)(ws + 4194304 + 4 * 131072);  // 128 KB

    gat_pre<<<512 + N * N / 64 / 4, 256, 0, stream>>>(input, adj, Wm, a, hT2, mask64,
                                                      es, es2, ed, ed2);
    gat_attn<<<B * (N / TI), 256, 0, stream>>>(hT2, es, es2, ed, ed2,
                                               (const unsigned*)mask64, out);
}

// Round 4
// 94.082 us; speedup vs baseline: 1.0132x; 1.0132x over previous
//
#include <hip/hip_runtime.h>
#include <math.h>

#define ALPHA 0.2f
#define LOG2E 1.4426950408889634f

constexpr int B = 32, N = 1024;
constexpr int TI = 32;          // i-rows per attn block (2 MFMA i-groups)

typedef __attribute__((ext_vector_type(8))) short short8;
typedef __attribute__((ext_vector_type(4))) float floatx4;

static __device__ __forceinline__ unsigned f32bf(float f) {
    unsigned u = __float_as_uint(f);
    return (u + 0x7FFFu + ((u >> 16) & 1u)) >> 16;   // RNE, no NaN inputs here
}

// ---------------- Kernel M: adj -> bitmask; also wa = W @ a_src/a_dst -----
// No LDS: stays at max occupancy for the latency-bound ballot grid.
__global__ __launch_bounds__(256) void gat_mask(const float* __restrict__ adj,
                                                const float* __restrict__ Wm,
                                                const float* __restrict__ a,
                                                unsigned long long* __restrict__ mask64,
                                                float* __restrict__ wa)
{
    const int lane = threadIdx.x & 63;
    const int wave = threadIdx.x >> 6;
    const int id   = blockIdx.x * 4 + wave;      // 0..16383
    const int i    = id >> 4;
    const int jc   = id & 15;
    const float av = adj[(size_t)i * N + jc * 64 + lane];
    const unsigned long long bal = __ballot(av > 0.5f);
    if (lane == 0) mask64[i * 16 + jc] = bal;

    if (blockIdx.x == 0 && wave == 0) {          // wa[k] = sum_c W[k][c]*a[c]
        float accs = 0.f, accd = 0.f;
#pragma unroll
        for (int c4 = 0; c4 < 16; ++c4) {
            const float4 wv = *(const float4*)&Wm[lane * 64 + c4 * 4];
            const float4 as = *(const float4*)&a[c4 * 4];
            const float4 ad = *(const float4*)&a[64 + c4 * 4];
            accs = fmaf(wv.x, as.x, fmaf(wv.y, as.y, fmaf(wv.z, as.z, fmaf(wv.w, as.w, accs))));
            accd = fmaf(wv.x, ad.x, fmaf(wv.y, ad.y, fmaf(wv.z, ad.z, fmaf(wv.w, ad.w, accd))));
        }
        wa[lane] = accs;
        wa[64 + lane] = accd;
    }
}

// ---------------- Kernel A: h(bf16) per batch in MFMA-B-fragment layout ----
// hT2[b][jt][t][cg][fq][il][e]: chunk (t,cg,fq,il) = h[j = jt*64+t*32+fq*8+e]
// [c = cg*16+il]. Also writes es=2^(s*log2e), es2=2^(0.2*s*log2e), ed, ed2
// so the attn kernel computes exp(lrelu(s+d)) = max(es*ed, es2*ed2)
// with no transcendentals (exp2 is monotone; lrelu commutes with the
// positive scale log2e).
__global__ __launch_bounds__(256) void gat_hs(const float* __restrict__ input,
                                              const float* __restrict__ Wm,
                                              const float* __restrict__ wa,
                                              unsigned short* __restrict__ hT2,
                                              float* __restrict__ es,
                                              float* __restrict__ es2,
                                              float* __restrict__ ed,
                                              float* __restrict__ ed2)
{
    __shared__ __align__(16) float ins[64 * 68];          // padded rows
    __shared__ __align__(16) unsigned short hsT[64 * 72]; // [c][row] padded
    __shared__ float red_s[256], red_d[256];
    __shared__ float wa_l[128];

    const int tid  = threadIdx.x;
    const int lane = tid & 63;
    const int wave = tid >> 6;
    const int row0 = blockIdx.x * 64;
    const int b    = row0 >> 10;
    const int jb   = row0 & 1023;

    float wreg[64];
#pragma unroll
    for (int k = 0; k < 64; ++k) wreg[k] = Wm[k * 64 + lane];   // W[:,lane]

    const float4* gin = (const float4*)(input + (size_t)row0 * 64);
#pragma unroll
    for (int s = 0; s < 4; ++s) {
        const int id = tid + 256 * s;
        *(float4*)&ins[(id >> 4) * 68 + (id & 15) * 4] = gin[id];
    }
    if (tid < 128) wa_l[tid] = wa[tid];
    __syncthreads();

    // h rows: wave handles rows [wave*16, wave*16+16)
    for (int r = 0; r < 16; ++r) {
        const int row = wave * 16 + r;
        float acc = 0.f;
#pragma unroll
        for (int k4 = 0; k4 < 16; ++k4) {
            const float4 iv = *(const float4*)&ins[row * 68 + k4 * 4];   // uniform
            acc = fmaf(iv.x, wreg[k4 * 4 + 0], acc);
            acc = fmaf(iv.y, wreg[k4 * 4 + 1], acc);
            acc = fmaf(iv.z, wreg[k4 * 4 + 2], acc);
            acc = fmaf(iv.w, wreg[k4 * 4 + 3], acc);
        }
        hsT[lane * 72 + row] = (unsigned short)f32bf(acc);   // transpose in LDS
    }

    // s_src/s_dst = ins @ wa (exact fp32, independent of bf16 h)
    {
        const int r = tid & 63, kq = tid >> 6;
        float as = 0.f, ad = 0.f;
#pragma unroll
        for (int t = 0; t < 4; ++t) {
            const float4 iv = *(const float4*)&ins[r * 68 + kq * 16 + t * 4];
            const float4 ws = *(const float4*)&wa_l[kq * 16 + t * 4];
            const float4 wd = *(const float4*)&wa_l[64 + kq * 16 + t * 4];
            as = fmaf(iv.x, ws.x, fmaf(iv.y, ws.y, fmaf(iv.z, ws.z, fmaf(iv.w, ws.w, as))));
            ad = fmaf(iv.x, wd.x, fmaf(iv.y, wd.y, fmaf(iv.z, wd.z, fmaf(iv.w, wd.w, ad))));
        }
        red_s[tid] = as;
        red_d[tid] = ad;
    }
    __syncthreads();

    if (tid < 64) {
        const float ss = (red_s[tid] + red_s[tid + 64] + red_s[tid + 128] + red_s[tid + 192]) * LOG2E;
        const float dd = (red_d[tid] + red_d[tid + 64] + red_d[tid + 128] + red_d[tid + 192]) * LOG2E;
        es [row0 + tid] = __builtin_amdgcn_exp2f(ss);
        es2[row0 + tid] = __builtin_amdgcn_exp2f(0.2f * ss);
        ed [row0 + tid] = __builtin_amdgcn_exp2f(dd);
        ed2[row0 + tid] = __builtin_amdgcn_exp2f(0.2f * dd);
    }

    // hT2 store: thread tid writes chunks q=2*tid, 2*tid+1 (32 B contiguous)
    {
        const int il2 = (tid & 7) * 2;
        const int fq  = (tid >> 3) & 3;
        const int cg  = (tid >> 5) & 3;
        const int t   = tid >> 7;
        const int c   = cg * 16 + il2;
        const int off = t * 32 + fq * 8;
        const short8 v0 = *(const short8*)&hsT[c * 72 + off];
        const short8 v1 = *(const short8*)&hsT[(c + 1) * 72 + off];
        unsigned short* g = hT2 + (((size_t)b * 16 + (jb >> 6)) << 12) + tid * 16;
        *(short8*)&g[0] = v0;
        *(short8*)&g[8] = v1;
    }
}

// ---------------- Kernel B: barrier-free, trans-free softmax + MFMA + ELU --
// TI=32, 1024 blocks, 34.8 KB LDS -> 4 blocks/CU, 4 waves/SIMD (R2 occupancy)
// with R3's 4-op inner element: p = mask ? max(E*D, E2*G) : 0.
// Zero LDS / zero barriers in the main loop; one epilogue barrier.
__global__ __launch_bounds__(256) void gat_attn(const unsigned short* __restrict__ hT2,
                                                const float* __restrict__ es,
                                                const float* __restrict__ es2,
                                                const float* __restrict__ ed,
                                                const float* __restrict__ ed2,
                                                const unsigned* __restrict__ mask32,
                                                float* __restrict__ out)
{
    __shared__ __align__(16) float red[4][TI][68];   // 34.8 KB
    __shared__ float pps[4][2][16];

    const int tid  = threadIdx.x;
    const int lane = tid & 63;
    const int w    = tid >> 6;
    // chunked XCD swizzle: 1024 blocks, 128 consecutive per XCD -> 4 batches/XCD
    const int bid  = (blockIdx.x & 7) * 128 + (blockIdx.x >> 3);
    const int b    = bid >> 5;
    const int i0   = (bid & 31) * TI;

    const int il  = lane & 15;
    const int fq  = lane >> 4;
    const int fsh = fq * 8;

    const float E0  = es [b * N + i0 + il];
    const float E1  = es [b * N + i0 + 16 + il];
    const float F0  = es2[b * N + i0 + il];
    const float F1  = es2[b * N + i0 + 16 + il];
    const float* edb  = ed  + b * N;
    const float* ed2b = ed2 + b * N;
    const unsigned* mb0 = mask32 + (size_t)(i0 + il) * 32;
    const unsigned* mb1 = mask32 + (size_t)(i0 + 16 + il) * 32;

    floatx4 acc[2][4];
#pragma unroll
    for (int ig = 0; ig < 2; ++ig)
#pragma unroll
        for (int cg = 0; cg < 4; ++cg) acc[ig][cg] = (floatx4){0.f, 0.f, 0.f, 0.f};
    float ps0 = 0.f, ps1 = 0.f;

    union Af { short8 v; unsigned u[4]; };

    for (int it = 0; it < 4; ++it) {
        const int jt = it * 4 + w;                    // this wave's j-tile
        const unsigned short* hp = hT2 + (((size_t)b * 16 + jt) << 12) + lane * 8;
        const uint2 m0 = *(const uint2*)&mb0[jt * 2];
        const uint2 m1 = *(const uint2*)&mb1[jt * 2];

#pragma unroll
        for (int t = 0; t < 2; ++t) {
            const int j0 = jt * 64 + t * 32 + fsh;
            const float4 d0 = *(const float4*)&edb[j0];
            const float4 d1 = *(const float4*)&edb[j0 + 4];
            const float4 g0 = *(const float4*)&ed2b[j0];
            const float4 g1 = *(const float4*)&ed2b[j0 + 4];
            short8 bf[4];
#pragma unroll
            for (int cg = 0; cg < 4; ++cg)
                bf[cg] = *(const short8*)(hp + (t * 4 + cg) * 512);

            float dv[8], gv[8];
            *(float4*)&dv[0] = d0; *(float4*)&dv[4] = d1;
            *(float4*)&gv[0] = g0; *(float4*)&gv[4] = g1;

            Af af[2];
#pragma unroll
            for (int ig = 0; ig < 2; ++ig) {
                const float E  = ig ? E1 : E0;
                const float F  = ig ? F1 : F0;
                const uint2 mw = ig ? m1 : m0;
                const unsigned mbits = (t ? mw.y : mw.x) >> fsh;
                float p[8];
#pragma unroll
                for (int e = 0; e < 8; ++e) {
                    const float x = fmaxf(E * dv[e], F * gv[e]);   // exp(lrelu)
                    p[e] = ((mbits >> e) & 1u) ? x : 0.f;
                }
                const float psl = ((p[0] + p[1]) + (p[2] + p[3])) + ((p[4] + p[5]) + (p[6] + p[7]));
                if (ig) ps1 += psl; else ps0 += psl;
#pragma unroll
                for (int q = 0; q < 4; ++q) {
                    unsigned r;
                    asm("v_cvt_pk_bf16_f32 %0, %1, %2" : "=v"(r) : "v"(p[q * 2]), "v"(p[q * 2 + 1]));
                    af[ig].u[q] = r;
                }
            }
#pragma unroll
            for (int ig = 0; ig < 2; ++ig)
#pragma unroll
                for (int cg = 0; cg < 4; ++cg)
                    acc[ig][cg] = __builtin_amdgcn_mfma_f32_16x16x32_bf16(af[ig].v, bf[cg], acc[ig][cg], 0, 0, 0);
        }
    }

    // row-sums: lanes {il, il+16, il+32, il+48} hold disjoint fq-slices
    ps0 += __shfl_xor(ps0, 16); ps0 += __shfl_xor(ps0, 32);
    ps1 += __shfl_xor(ps1, 16); ps1 += __shfl_xor(ps1, 32);
    if (lane < 16) { pps[w][0][lane] = ps0; pps[w][1][lane] = ps1; }

    // C/D layout: col = cg*16 + il, row = ig*16 + fq*4 + r
#pragma unroll
    for (int ig = 0; ig < 2; ++ig)
#pragma unroll
        for (int cg = 0; cg < 4; ++cg)
#pragma unroll
            for (int r = 0; r < 4; ++r)
                red[w][ig * 16 + fq * 4 + r][cg * 16 + il] = acc[ig][cg][r];
    __syncthreads();

    // cross-wave reduce + softmax divide + ELU + store (thread: 1 row x 8 cols)
    const int row = tid >> 3;
    const int c0  = (tid & 7) * 8;
    float4 oa = {0.f, 0.f, 0.f, 0.f}, ob = {0.f, 0.f, 0.f, 0.f};
#pragma unroll
    for (int ww = 0; ww < 4; ++ww) {
        const float4 xa = *(const float4*)&red[ww][row][c0];
        const float4 xb = *(const float4*)&red[ww][row][c0 + 4];
        oa.x += xa.x; oa.y += xa.y; oa.z += xa.z; oa.w += xa.w;
        ob.x += xb.x; ob.y += xb.y; ob.z += xb.z; ob.w += xb.w;
    }
    const int ig = row >> 4, rl = row & 15;
    const float inv = 1.f / (pps[0][ig][rl] + pps[1][ig][rl] + pps[2][ig][rl] + pps[3][ig][rl]);
    float o[8] = {oa.x, oa.y, oa.z, oa.w, ob.x, ob.y, ob.z, ob.w};
#pragma unroll
    for (int e = 0; e < 8; ++e) {
        const float hp = o[e] * inv;
        o[e] = hp > 0.f ? hp : __expf(hp) - 1.f;      // ELU
    }
    float* op = out + ((size_t)(b * N + i0 + row)) * 64 + c0;
    *(float4*)&op[0] = *(float4*)&o[0];
    *(float4*)&op[4] = *(float4*)&o[4];
}

extern "C" void kernel_launch(void* const* d_in, const int* in_sizes, int n_in,
                              void* d_out, int out_size, void* d_ws, size_t ws_size,
                              hipStream_t stream) {
    const float* input = (const float*)d_in[0];
    const float* adj   = (const float*)d_in[1];
    const float* Wm    = (const float*)d_in[2];
    const float* a     = (const float*)d_in[3];
    float* out = (float*)d_out;

    char* ws = (char*)d_ws;
    unsigned short* hT2 = (unsigned short*)ws;                     // 4 MB
    float* es  = (float*)(ws + 4194304);                           // 128 KB
    float* es2 = (float*)(ws + 4194304 + 131072);                  // 128 KB
    float* ed  = (float*)(ws + 4194304 + 2 * 131072);              // 128 KB
    float* ed2 = (float*)(ws + 4194304 + 3 * 131072);              // 128 KB
    unsigned long long* mask64 = (unsigned long long*)(ws + 4194304 + 4 * 131072);  // 128 KB
    float* wa = (float*)(ws + 4194304 + 5 * 131072);               // 512 B

    gat_mask<<<N * N / 64 / 4, 256, 0, stream>>>(adj, Wm, a, mask64, wa);
    gat_hs<<<B * N / 64, 256, 0, stream>>>(input, Wm, wa, hT2, es, es2, ed, ed2);
    gat_attn<<<B * (N / TI), 256, 0, stream>>>(hT2, es, es2, ed, ed2,
                                               (const unsigned*)mask64, out);
}

// Round 5
// 89.789 us; speedup vs baseline: 1.0616x; 1.0478x over previous
//
#include <hip/hip_runtime.h>
#include <math.h>

#define ALPHA 0.2f
#define LOG2E 1.4426950408889634f

constexpr int B = 32, N = 1024;
constexpr int TI = 32;          // i-rows per attn block (2 MFMA i-groups)

typedef __attribute__((ext_vector_type(8))) short short8;
typedef __attribute__((ext_vector_type(4))) float floatx4;

static __device__ __forceinline__ unsigned f32bf(float f) {
    unsigned u = __float_as_uint(f);
    return (u + 0x7FFFu + ((u >> 16) & 1u)) >> 16;   // RNE, no NaN inputs here
}

// ---------------- Kernel A (fused): h(bf16) + s-vectors + wa + adj mask ----
// hT2[b][jt][t][cg][fq][il][e]: chunk (t,cg,fq,il) = h[j = jt*64+t*32+fq*8+e]
// [c = cg*16+il], so one dwordx4 per (cg,t) in the attn kernel reads a full
// wave-coalesced 1024B B-fragment. s vectors pre-scaled by log2(e).
// Mask fusion: each block handles 32 of the 16384 (i,jc) ballot units; the
// 8 adj loads/lane issue at kernel entry and the ballots retire at the end,
// hiding HBM latency under the h-compute.
__global__ __launch_bounds__(256) void gat_hs(const float* __restrict__ input,
                                              const float* __restrict__ adj,
                                              const float* __restrict__ Wm,
                                              const float* __restrict__ a,
                                              unsigned short* __restrict__ hT2,
                                              float* __restrict__ ssrc,
                                              float* __restrict__ sdst,
                                              unsigned long long* __restrict__ mask64)
{
    __shared__ __align__(16) float ins[64 * 68];          // padded rows
    __shared__ __align__(16) unsigned short hsT[64 * 72]; // [c][row] padded
    __shared__ float red_s[256], red_d[256];
    __shared__ float wa_l[128];

    const int tid  = threadIdx.x;
    const int lane = tid & 63;
    const int wave = tid >> 6;
    const int row0 = blockIdx.x * 64;
    const int b    = row0 >> 10;
    const int jb   = row0 & 1023;

    // ---- issue mask-role adj loads first (consumed at the very end) ----
    const int unit0 = blockIdx.x * 32 + wave * 8;
    float av[8];
#pragma unroll
    for (int k = 0; k < 8; ++k) {
        const int u = unit0 + k;
        av[k] = adj[((size_t)(u >> 4) << 10) + (u & 15) * 64 + lane];
    }

    float wreg[64];
#pragma unroll
    for (int k = 0; k < 64; ++k) wreg[k] = Wm[k * 64 + lane];   // W[:,lane]

    const float4* gin = (const float4*)(input + (size_t)row0 * 64);
#pragma unroll
    for (int s = 0; s < 4; ++s) {
        const int id = tid + 256 * s;
        *(float4*)&ins[(id >> 4) * 68 + (id & 15) * 4] = gin[id];
    }
    if (wave == 0) {                             // wa[k] = sum_c W[k][c]*a[c]
        float accs = 0.f, accd = 0.f;
#pragma unroll
        for (int c4 = 0; c4 < 16; ++c4) {
            const float4 wv = *(const float4*)&Wm[lane * 64 + c4 * 4];
            const float4 as = *(const float4*)&a[c4 * 4];
            const float4 ad = *(const float4*)&a[64 + c4 * 4];
            accs = fmaf(wv.x, as.x, fmaf(wv.y, as.y, fmaf(wv.z, as.z, fmaf(wv.w, as.w, accs))));
            accd = fmaf(wv.x, ad.x, fmaf(wv.y, ad.y, fmaf(wv.z, ad.z, fmaf(wv.w, ad.w, accd))));
        }
        wa_l[lane] = accs;
        wa_l[64 + lane] = accd;
    }
    __syncthreads();

    // h rows: wave handles rows [wave*16, wave*16+16)
    for (int r = 0; r < 16; ++r) {
        const int row = wave * 16 + r;
        float acc = 0.f;
#pragma unroll
        for (int k4 = 0; k4 < 16; ++k4) {
            const float4 iv = *(const float4*)&ins[row * 68 + k4 * 4];   // uniform
            acc = fmaf(iv.x, wreg[k4 * 4 + 0], acc);
            acc = fmaf(iv.y, wreg[k4 * 4 + 1], acc);
            acc = fmaf(iv.z, wreg[k4 * 4 + 2], acc);
            acc = fmaf(iv.w, wreg[k4 * 4 + 3], acc);
        }
        hsT[lane * 72 + row] = (unsigned short)f32bf(acc);   // transpose in LDS
    }

    // s_src/s_dst = ins @ wa (exact fp32, independent of bf16 h)
    {
        const int r = tid & 63, kq = tid >> 6;
        float as = 0.f, ad = 0.f;
#pragma unroll
        for (int t = 0; t < 4; ++t) {
            const float4 iv = *(const float4*)&ins[r * 68 + kq * 16 + t * 4];
            const float4 ws = *(const float4*)&wa_l[kq * 16 + t * 4];
            const float4 wd = *(const float4*)&wa_l[64 + kq * 16 + t * 4];
            as = fmaf(iv.x, ws.x, fmaf(iv.y, ws.y, fmaf(iv.z, ws.z, fmaf(iv.w, ws.w, as))));
            ad = fmaf(iv.x, wd.x, fmaf(iv.y, wd.y, fmaf(iv.z, wd.z, fmaf(iv.w, wd.w, ad))));
        }
        red_s[tid] = as;
        red_d[tid] = ad;
    }
    __syncthreads();

    if (tid < 64) {
        ssrc[row0 + tid] = (red_s[tid] + red_s[tid + 64] + red_s[tid + 128] + red_s[tid + 192]) * LOG2E;
        sdst[row0 + tid] = (red_d[tid] + red_d[tid + 64] + red_d[tid + 128] + red_d[tid + 192]) * LOG2E;
    }

    // hT2 store: thread tid writes chunks q=2*tid, 2*tid+1 (32 B contiguous)
    {
        const int il2 = (tid & 7) * 2;
        const int fq  = (tid >> 3) & 3;
        const int cg  = (tid >> 5) & 3;
        const int t   = tid >> 7;
        const int c   = cg * 16 + il2;
        const int off = t * 32 + fq * 8;
        const short8 v0 = *(const short8*)&hsT[c * 72 + off];
        const short8 v1 = *(const short8*)&hsT[(c + 1) * 72 + off];
        unsigned short* g = hT2 + (((size_t)b * 16 + (jb >> 6)) << 12) + tid * 16;
        *(short8*)&g[0] = v0;
        *(short8*)&g[8] = v1;
    }

    // ---- mask-role ballots (adj loads issued at entry are long done) ----
#pragma unroll
    for (int k = 0; k < 8; ++k) {
        const int u = unit0 + k;
        const unsigned long long bal = __ballot(av[k] > 0.5f);
        if (lane == 0) mask64[(u >> 4) * 16 + (u & 15)] = bal;
    }
}

// ---------------- Kernel B: barrier-free fused softmax + MFMA PV + ELU -----
// TI=32 rows per block; wave w owns j-tiles {it*4+w}. B-fragments load
// directly from hT2 (1024B contiguous per wave per load, L2-resident).
// Zero LDS / zero barriers in the main loop; one epilogue barrier for the
// 4-way cross-wave accumulator + row-sum reduction.
__global__ __launch_bounds__(256) void gat_attn(const unsigned short* __restrict__ hT2,
                                                const float* __restrict__ ssrc,
                                                const float* __restrict__ sdst,
                                                const unsigned* __restrict__ mask32,
                                                float* __restrict__ out)
{
    __shared__ __align__(16) float red[4][TI][68];   // 34.8 KB
    __shared__ float pps[4][2][16];

    const int tid  = threadIdx.x;
    const int lane = tid & 63;
    const int w    = tid >> 6;
    const int b    = blockIdx.x >> 5;           // 32 i-tiles per batch
    const int i0   = (blockIdx.x & 31) * TI;

    const int il = lane & 15;
    const int fq = lane >> 4;

    const float ssq0 = ssrc[b * N + i0 + il];         // already *log2e
    const float ssq1 = ssrc[b * N + i0 + 16 + il];
    const float* sd = sdst + b * N;
    const unsigned* mb0 = mask32 + (size_t)(i0 + il) * 32;
    const unsigned* mb1 = mask32 + (size_t)(i0 + 16 + il) * 32;

    floatx4 acc[2][4];
#pragma unroll
    for (int ig = 0; ig < 2; ++ig)
#pragma unroll
        for (int cg = 0; cg < 4; ++cg) acc[ig][cg] = (floatx4){0.f, 0.f, 0.f, 0.f};
    float ps0 = 0.f, ps1 = 0.f;

    union Af { short8 v; unsigned u[4]; };

    for (int it = 0; it < 4; ++it) {
        const int jt = it * 4 + w;                    // this wave's j-tile
        // ---- issue scalar-ish loads first (p-compute waits only on these)
        const float4 s0 = *(const float4*)&sd[jt * 64 + fq * 8];
        const float4 s1 = *(const float4*)&sd[jt * 64 + fq * 8 + 4];
        const float4 s2 = *(const float4*)&sd[jt * 64 + 32 + fq * 8];
        const float4 s3 = *(const float4*)&sd[jt * 64 + 32 + fq * 8 + 4];
        const uint2 m0 = *(const uint2*)&mb0[jt * 2];
        const uint2 m1 = *(const uint2*)&mb1[jt * 2];
        // ---- B-fragments: one dwordx4 per (cg,t), wave-contiguous 1024B
        const unsigned short* hp = hT2 + (((size_t)b * 16 + jt) << 12) + lane * 8;
        short8 bf[4][2];
#pragma unroll
        for (int cg = 0; cg < 4; ++cg) {
            bf[cg][0] = *(const short8*)(hp + (0 * 4 + cg) * 512);
            bf[cg][1] = *(const short8*)(hp + (1 * 4 + cg) * 512);
        }

        float sv[16];
        *(float4*)&sv[0]  = s0;
        *(float4*)&sv[4]  = s1;
        *(float4*)&sv[8]  = s2;
        *(float4*)&sv[12] = s3;

        Af af[2][2];
#pragma unroll
        for (int ig = 0; ig < 2; ++ig) {
            const float ssq = ig ? ssq1 : ssq0;
            const uint2 mw = ig ? m1 : m0;
            float psl = 0.f;
#pragma unroll
            for (int t = 0; t < 2; ++t) {
                const unsigned mbits = (t ? mw.y : mw.x) >> (fq * 8);
                float p[8];
#pragma unroll
                for (int e = 0; e < 8; ++e) {
                    float x = ssq + sv[t * 8 + e];
                    x = fmaxf(x, ALPHA * x);          // leaky-relu (log2 domain)
                    x = __builtin_amdgcn_exp2f(x);
                    p[e] = ((mbits >> e) & 1u) ? x : 0.f;
                }
                psl += ((p[0] + p[1]) + (p[2] + p[3])) + ((p[4] + p[5]) + (p[6] + p[7]));
#pragma unroll
                for (int q = 0; q < 4; ++q) {
                    unsigned r;
                    asm("v_cvt_pk_bf16_f32 %0, %1, %2" : "=v"(r) : "v"(p[q * 2]), "v"(p[q * 2 + 1]));
                    af[ig][t].u[q] = r;
                }
            }
            if (ig) ps1 += psl; else ps0 += psl;
        }

#pragma unroll
        for (int ig = 0; ig < 2; ++ig)
#pragma unroll
            for (int cg = 0; cg < 4; ++cg) {
                acc[ig][cg] = __builtin_amdgcn_mfma_f32_16x16x32_bf16(af[ig][0].v, bf[cg][0], acc[ig][cg], 0, 0, 0);
                acc[ig][cg] = __builtin_amdgcn_mfma_f32_16x16x32_bf16(af[ig][1].v, bf[cg][1], acc[ig][cg], 0, 0, 0);
            }
    }

    // row-sums: lanes {il, il+16, il+32, il+48} hold disjoint fq-slices
    ps0 += __shfl_xor(ps0, 16); ps0 += __shfl_xor(ps0, 32);
    ps1 += __shfl_xor(ps1, 16); ps1 += __shfl_xor(ps1, 32);
    if (lane < 16) { pps[w][0][lane] = ps0; pps[w][1][lane] = ps1; }

    // C/D layout: col = cg*16 + il, row = ig*16 + fq*4 + r
#pragma unroll
    for (int ig = 0; ig < 2; ++ig)
#pragma unroll
        for (int cg = 0; cg < 4; ++cg)
#pragma unroll
            for (int r = 0; r < 4; ++r)
                red[w][ig * 16 + fq * 4 + r][cg * 16 + il] = acc[ig][cg][r];
    __syncthreads();

    // cross-wave reduce + softmax divide + ELU + store (thread: 1 row x 8 cols)
    const int row = tid >> 3;
    const int c0  = (tid & 7) * 8;
    float4 oa = {0.f, 0.f, 0.f, 0.f}, ob = {0.f, 0.f, 0.f, 0.f};
#pragma unroll
    for (int ww = 0; ww < 4; ++ww) {
        const float4 xa = *(const float4*)&red[ww][row][c0];
        const float4 xb = *(const float4*)&red[ww][row][c0 + 4];
        oa.x += xa.x; oa.y += xa.y; oa.z += xa.z; oa.w += xa.w;
        ob.x += xb.x; ob.y += xb.y; ob.z += xb.z; ob.w += xb.w;
    }
    const int ig = row >> 4, rl = row & 15;
    const float inv = 1.f / (pps[0][ig][rl] + pps[1][ig][rl] + pps[2][ig][rl] + pps[3][ig][rl]);
    float o[8] = {oa.x, oa.y, oa.z, oa.w, ob.x, ob.y, ob.z, ob.w};
#pragma unroll
    for (int e = 0; e < 8; ++e) {
        const float hp = o[e] * inv;
        o[e] = hp > 0.f ? hp : __expf(hp) - 1.f;      // ELU
    }
    float* op = out + ((size_t)(b * N + i0 + row)) * 64 + c0;
    *(float4*)&op[0] = *(float4*)&o[0];
    *(float4*)&op[4] = *(float4*)&o[4];
}

extern "C" void kernel_launch(void* const* d_in, const int* in_sizes, int n_in,
                              void* d_out, int out_size, void* d_ws, size_t ws_size,
                              hipStream_t stream) {
    const float* input = (const float*)d_in[0];
    const float* adj   = (const float*)d_in[1];
    const float* Wm    = (const float*)d_in[2];
    const float* a     = (const float*)d_in[3];
    float* out = (float*)d_out;

    char* ws = (char*)d_ws;
    unsigned short* hT2 = (unsigned short*)ws;                     // 4 MB
    float* ssrc = (float*)(ws + 4194304);                          // 128 KB
    float* sdst = (float*)(ws + 4194304 + 131072);                 // 128 KB
    unsigned long long* mask64 = (unsigned long long*)(ws + 4194304 + 2 * 131072);  // 128 KB

    gat_hs<<<B * N / 64, 256, 0, stream>>>(input, adj, Wm, a, hT2, ssrc, sdst, mask64);
    gat_attn<<<B * (N / TI), 256, 0, stream>>>(hT2, ssrc, sdst, (const unsigned*)mask64, out);
}